// Round 5
// baseline (889.161 us; speedup 1.0000x reference)
//
#include <hip/hip_runtime.h>
#include <math.h>

#define B_   32
#define SEQ_ 2048
#define DIM_ 512
#define KSEL 128

typedef _Float16 f16;
typedef _Float16 half8 __attribute__((ext_vector_type(8)));
typedef float floatx4 __attribute__((ext_vector_type(4)));

#define LSTR2 32   // linear LDS row stride in halves (64B rows) for gll staging

__device__ __forceinline__ float gelu_exact(float v) {
  return 0.5f * v * (1.0f + erff(v * 0.70710678118654752440f));
}

// ======================= stats kernels =======================
__global__ __launch_bounds__(256) void rowstats512(const float* __restrict__ X,
                                                   float* __restrict__ mean,
                                                   float* __restrict__ rstd) {
  int row = blockIdx.x * 4 + (threadIdx.x >> 6);
  int l = threadIdx.x & 63;
  const float4* p = (const float4*)(X + (size_t)row * 512);
  float4 v0 = p[l * 2], v1 = p[l * 2 + 1];
  float s = v0.x + v0.y + v0.z + v0.w + v1.x + v1.y + v1.z + v1.w;
  float q = v0.x*v0.x + v0.y*v0.y + v0.z*v0.z + v0.w*v0.w
          + v1.x*v1.x + v1.y*v1.y + v1.z*v1.z + v1.w*v1.w;
#pragma unroll
  for (int off = 32; off > 0; off >>= 1) {
    s += __shfl_down(s, off);
    q += __shfl_down(q, off);
  }
  if (l == 0) {
    float m = s * (1.0f / 512.0f);
    float var = q * (1.0f / 512.0f) - m * m;
    mean[row] = m;
    rstd[row] = rsqrtf(var + 1e-5f);
  }
}

__global__ __launch_bounds__(256) void rowstats512_f16(const f16* __restrict__ X,
                                                       float* __restrict__ mean,
                                                       float* __restrict__ rstd) {
  int row = blockIdx.x * 4 + (threadIdx.x >> 6);
  int l = threadIdx.x & 63;
  half8 h = *(const half8*)(X + (size_t)row * 512 + l * 8);
  float s = 0.f, q = 0.f;
#pragma unroll
  for (int i = 0; i < 8; ++i) { float v = (float)h[i]; s += v; q += v * v; }
#pragma unroll
  for (int off = 32; off > 0; off >>= 1) {
    s += __shfl_down(s, off);
    q += __shfl_down(q, off);
  }
  if (l == 0) {
    float m = s * (1.0f / 512.0f);
    float var = q * (1.0f / 512.0f) - m * m;
    mean[row] = m;
    rstd[row] = rsqrtf(var + 1e-5f);
  }
}

__global__ __launch_bounds__(512) void colstats_part(const f16* __restrict__ xtok,
                                                     float2* __restrict__ part) {
  int b = blockIdx.x >> 3, pr = blockIdx.x & 7;
  int d = threadIdx.x;
  const f16* src = xtok + ((size_t)b * SEQ_ + (size_t)pr * 256) * 512 + d;
  float s = 0.f, q = 0.f;
#pragma unroll 4
  for (int i = 0; i < 256; ++i) {
    float v = (float)src[(size_t)i * 512];
    s += v; q += v * v;
  }
  part[(size_t)blockIdx.x * 512 + d] = make_float2(s, q);
}

__global__ __launch_bounds__(256) void colstats_fin(const float2* __restrict__ part,
                                                    float* __restrict__ mean,
                                                    float* __restrict__ rstd) {
  int idx = blockIdx.x * 256 + threadIdx.x;
  int b = idx >> 9;
  float s = 0.f, q = 0.f;
#pragma unroll
  for (int p = 0; p < 8; ++p) {
    float2 v = part[((size_t)(b * 8 + p)) * 512 + (idx & 511)];
    s += v.x; q += v.y;
  }
  float m = s * (1.0f / 2048.0f);
  mean[idx] = m;
  rstd[idx] = rsqrtf(q * (1.0f / 2048.0f) - m * m + 1e-5f);
}

// ======================= transpose / convert =======================
template <typename T>
__global__ __launch_bounds__(256) void transpose_cvt(const T* __restrict__ src,
                                                     f16* __restrict__ dst,
                                                     int R, int C, long sb, long db) {
  __shared__ float tile[32][33];
  const T* s = src + (long)blockIdx.z * sb;
  f16* d = dst + (long)blockIdx.z * db;
  int c0 = blockIdx.x * 32, r0 = blockIdx.y * 32;
  int tx = threadIdx.x, ty = threadIdx.y;
#pragma unroll
  for (int i = 0; i < 4; ++i) {
    int r = r0 + ty + i * 8, c = c0 + tx;
    if (r < R && c < C) tile[ty + i * 8][tx] = (float)s[(long)r * C + c];
  }
  __syncthreads();
#pragma unroll
  for (int i = 0; i < 4; ++i) {
    int c = c0 + ty + i * 8, r = r0 + tx;
    if (c < C && r < R) d[(long)c * R + r] = (f16)tile[tx][ty + i * 8];
  }
}

// LN2-apply + transpose: A2[b][d][s] = (xtok[b][s][d]-m2[b,d])*r2[b,d]*g2[s]+bl2[s]
__global__ __launch_bounds__(256) void trans2_kernel(const f16* __restrict__ xtok,
    const float* __restrict__ mean2, const float* __restrict__ rstd2,
    const float* __restrict__ g2, const float* __restrict__ bl2,
    f16* __restrict__ A2) {
  __shared__ float tile[32][33];
  int b = blockIdx.z;
  const f16* src = xtok + (long)b * SEQ_ * 512;
  f16* dst = A2 + (long)b * 512 * SEQ_;
  int d0 = blockIdx.x * 32, s0 = blockIdx.y * 32;
  int tx = threadIdx.x, ty = threadIdx.y;
  float m = mean2[b * 512 + d0 + tx];
  float rs = rstd2[b * 512 + d0 + tx];
#pragma unroll
  for (int i = 0; i < 4; ++i) {
    int s = s0 + ty + i * 8;
    float v = (float)src[(long)s * 512 + d0 + tx];
    tile[ty + i * 8][tx] = (v - m) * rs * g2[s] + bl2[s];
  }
  __syncthreads();
#pragma unroll
  for (int i = 0; i < 4; ++i) {
    int d = d0 + ty + i * 8, s = s0 + tx;
    dst[(long)d * SEQ_ + s] = (f16)tile[tx][ty + i * 8];
  }
}

// ======================= 128-tile GEMM core (m97 structure) =======================
__device__ __forceinline__ void stage_gll(const f16* __restrict__ src, long ld,
                                          int row0, int k0, f16* S, int t) {
  int w = t >> 6, lane = t & 63;
  int r = lane >> 2, c8 = (lane & 3) * 8;
#pragma unroll
  for (int i = 0; i < 2; ++i) {
    int chunk = w * 2 + i;
    const f16* g = src + (long)(row0 + chunk * 16 + r) * ld + k0 + c8;
    f16* l = S + chunk * 16 * LSTR2;
    __builtin_amdgcn_global_load_lds(
        (const __attribute__((address_space(1))) void*)g,
        (__attribute__((address_space(3))) void*)l, 16, 0, 0);
  }
}

__device__ __forceinline__ void stage_a_ln_f32(const float* __restrict__ src, long ld,
    const float* __restrict__ mean, const float* __restrict__ rstd,
    const float* __restrict__ g, const float* __restrict__ bl,
    int row0, int k0, f16* S, int t) {
  int row = t >> 1, kc = (t & 1) * 16;
  int r = row0 + row, c = k0 + kc;
  float m = mean[r], sd = rstd[r];
  const float* p = src + (long)r * ld + c;
  float v[16], gv[16], bv[16];
#pragma unroll
  for (int i = 0; i < 4; ++i) {
    float4 q = ((const float4*)p)[i];
    v[i*4+0]=q.x; v[i*4+1]=q.y; v[i*4+2]=q.z; v[i*4+3]=q.w;
    float4 gq = ((const float4*)(g + c))[i];
    gv[i*4+0]=gq.x; gv[i*4+1]=gq.y; gv[i*4+2]=gq.z; gv[i*4+3]=gq.w;
    float4 bq = ((const float4*)(bl + c))[i];
    bv[i*4+0]=bq.x; bv[i*4+1]=bq.y; bv[i*4+2]=bq.z; bv[i*4+3]=bq.w;
  }
  half8 o0, o1;
#pragma unroll
  for (int i = 0; i < 8; ++i) {
    o0[i] = (f16)((v[i] - m) * sd * gv[i] + bv[i]);
    o1[i] = (f16)((v[i + 8] - m) * sd * gv[i + 8] + bv[i + 8]);
  }
  *(half8*)(S + row * LSTR2 + kc) = o0;
  *(half8*)(S + row * LSTR2 + kc + 8) = o1;
}

__device__ __forceinline__ void stage_a_ln_f16(const f16* __restrict__ src, long ld,
    const float* __restrict__ mean, const float* __restrict__ rstd,
    const float* __restrict__ g, const float* __restrict__ bl,
    int row0, int k0, f16* S, int t) {
  int row = t >> 1, kc = (t & 1) * 16;
  int r = row0 + row, c = k0 + kc;
  float m = mean[r], sd = rstd[r];
  const f16* p = src + (long)r * ld + c;
  half8 h0 = *(const half8*)(p);
  half8 h1 = *(const half8*)(p + 8);
  float gv[16], bv[16];
#pragma unroll
  for (int i = 0; i < 4; ++i) {
    float4 gq = ((const float4*)(g + c))[i];
    gv[i*4+0]=gq.x; gv[i*4+1]=gq.y; gv[i*4+2]=gq.z; gv[i*4+3]=gq.w;
    float4 bq = ((const float4*)(bl + c))[i];
    bv[i*4+0]=bq.x; bv[i*4+1]=bq.y; bv[i*4+2]=bq.z; bv[i*4+3]=bq.w;
  }
  half8 o0, o1;
#pragma unroll
  for (int i = 0; i < 8; ++i) {
    o0[i] = (f16)(((float)h0[i] - m) * sd * gv[i] + bv[i]);
    o1[i] = (f16)(((float)h1[i] - m) * sd * gv[i + 8] + bv[i + 8]);
  }
  *(half8*)(S + row * LSTR2 + kc) = o0;
  *(half8*)(S + row * LSTR2 + kc + 8) = o1;
}

__device__ __forceinline__ void mfma_step(const f16* As, const f16* Bs, int lane,
                                          int wr, int wc, floatx4 acc[4][4]) {
  int kc = (lane >> 4) * 8;
  int rl = lane & 15;
  half8 a[4], b[4];
#pragma unroll
  for (int mi = 0; mi < 4; ++mi)
    a[mi] = *(const half8*)(As + (wr * 64 + mi * 16 + rl) * LSTR2 + kc);
#pragma unroll
  for (int ni = 0; ni < 4; ++ni)
    b[ni] = *(const half8*)(Bs + (wc * 64 + ni * 16 + rl) * LSTR2 + kc);
#pragma unroll
  for (int mi = 0; mi < 4; ++mi)
#pragma unroll
    for (int ni = 0; ni < 4; ++ni)
      acc[mi][ni] = __builtin_amdgcn_mfma_f32_16x16x32_f16(a[mi], b[ni], acc[mi][ni], 0, 0, 0);
}

#define GEMM_PROLOG \
  __shared__ __attribute__((aligned(16))) f16 As[128 * LSTR2]; \
  __shared__ __attribute__((aligned(16))) f16 Bs[128 * LSTR2]; \
  int t = threadIdx.x; \
  int lane = t & 63, w = t >> 6, wr = w >> 1, wc = w & 1; \
  floatx4 acc[4][4]; \
  _Pragma("unroll") for (int mi = 0; mi < 4; ++mi) \
  _Pragma("unroll") for (int ni = 0; ni < 4; ++ni) acc[mi][ni] = (floatx4){0.f,0.f,0.f,0.f};

// ---- G1 ----
__global__ __launch_bounds__(256) void g1_kernel(const float* __restrict__ x,
    const float* __restrict__ mean, const float* __restrict__ rstd,
    const float* __restrict__ g1, const float* __restrict__ bl1,
    const f16* __restrict__ W1T, const float* __restrict__ b1,
    f16* __restrict__ xtok) {
  GEMM_PROLOG
  int m0 = blockIdx.y * 128, n0 = blockIdx.x * 128;
  for (int k0 = 0; k0 < 512; k0 += 32) {
    stage_a_ln_f32(x, 512, mean, rstd, g1, bl1, m0, k0, As, t);
    stage_gll(W1T, 512, n0, k0, Bs, t);
    __syncthreads();
    mfma_step(As, Bs, lane, wr, wc, acc);
    __syncthreads();
  }
#pragma unroll
  for (int mi = 0; mi < 4; ++mi)
#pragma unroll
    for (int ni = 0; ni < 4; ++ni) {
      int c = n0 + wc * 64 + ni * 16 + (lane & 15);
      float bias = b1[c];
      int r0 = m0 + wr * 64 + mi * 16 + (lane >> 4) * 4;
#pragma unroll
      for (int j = 0; j < 4; ++j)
        xtok[(long)(r0 + j) * 512 + c] = (f16)gelu_exact(acc[mi][ni][j] + bias);
    }
}

// ======================= G2: 256x256 BK64 deep-pipelined engine =======================
// M = s' (2048, rows of W2T), N = d (512, rows of A2), K = s (2048).
// 8 waves (2M x 4N), per-wave 128x64 out. 2 LDS buffers, T2 swizzle, T5 setprio.
__device__ __forceinline__ void stage_tile256(const f16* __restrict__ srcbase, long ld,
                                              int k0, f16* dst, int tid) {
  int w = tid >> 6, l = tid & 63;
  int colh = ((l & 7) ^ (l >> 3)) << 3;   // pre-swizzled source column (halves)
  int rsub = w * 8 + (l >> 3);
#pragma unroll
  for (int q = 0; q < 4; ++q) {
    const f16* g = srcbase + (long)(q * 64 + rsub) * ld + k0 + colh;
    f16* lp = dst + (long)(q * 512 + w * 64) * 8;  // wave-uniform; HW adds lane*16B
    __builtin_amdgcn_global_load_lds(
        (const __attribute__((address_space(1))) void*)g,
        (__attribute__((address_space(3))) void*)lp, 16, 0, 0);
  }
}

__device__ __forceinline__ half8 frag_swz(const f16* buf, int row, int kslot, int rl) {
  // LDS rows are 64 halves (128B); swizzle: slot' = kslot ^ (row&7), row&7 == rl&7 here
  return *(const half8*)(buf + (long)row * 64 + (((kslot ^ (rl & 7))) << 3));
}

__global__ __launch_bounds__(512, 2) void g2_8p(const f16* __restrict__ W2T,
    const f16* __restrict__ A2, const float* __restrict__ b2,
    const f16* __restrict__ xtok, f16* __restrict__ xsum) {
  __shared__ __attribute__((aligned(16))) f16 Abuf[2][256 * 64];
  __shared__ __attribute__((aligned(16))) f16 Bbuf[2][256 * 64];
  int tid = threadIdx.x;
  int l = tid & 63, w = tid >> 6;
  int wr = w >> 2, wc = w & 3;          // 2M x 4N wave grid
  int rl = l & 15, sl = l >> 4;         // fragment lane coords
  int b = blockIdx.z;
  int m0 = blockIdx.y * 256;            // s' base
  int n0 = blockIdx.x * 256;            // d base
  const f16* Am = W2T + (long)m0 * SEQ_;
  const f16* Bm = A2 + (long)b * 512 * SEQ_ + (long)n0 * SEQ_;
  const f16* xtb = xtok + (long)b * SEQ_ * 512;
  f16* xsb = xsum + (long)b * SEQ_ * 512;

  floatx4 acc[8][4];
#pragma unroll
  for (int mf = 0; mf < 8; ++mf)
#pragma unroll
    for (int nf = 0; nf < 4; ++nf) acc[mf][nf] = (floatx4){0.f, 0.f, 0.f, 0.f};

  const int NT = SEQ_ / 64;  // 32 K-tiles
  // prologue: stage tile 0
  stage_tile256(Am, SEQ_, 0, Abuf[0], tid);
  stage_tile256(Bm, SEQ_, 0, Bbuf[0], tid);
  __syncthreads();   // drains vmcnt(0): tile 0 resident

  for (int t = 0; t < NT; ++t) {
    int c = t & 1;
    const f16* Ab = Abuf[c];
    const f16* Bb = Bbuf[c];
    half8 afr[4], bfr[4];

    // ---- phase 0: stage A(t+1); read b(kk0), a_lo(kk0); MFMA m0-3 kk0
    if (t + 1 < NT) stage_tile256(Am, SEQ_, (t + 1) * 64, Abuf[c ^ 1], tid);
#pragma unroll
    for (int nf = 0; nf < 4; ++nf) bfr[nf] = frag_swz(Bb, wc * 64 + nf * 16 + rl, sl, rl);
#pragma unroll
    for (int mf = 0; mf < 4; ++mf) afr[mf] = frag_swz(Ab, wr * 128 + mf * 16 + rl, sl, rl);
    __builtin_amdgcn_s_barrier();
    __builtin_amdgcn_s_setprio(1);
#pragma unroll
    for (int mf = 0; mf < 4; ++mf)
#pragma unroll
      for (int nf = 0; nf < 4; ++nf)
        acc[mf][nf] = __builtin_amdgcn_mfma_f32_16x16x32_f16(afr[mf], bfr[nf], acc[mf][nf], 0, 0, 0);
    __builtin_amdgcn_s_setprio(0);
    __builtin_amdgcn_s_barrier();

    // ---- phase 1: stage B(t+1); read a_hi(kk0); MFMA m4-7 kk0
    if (t + 1 < NT) stage_tile256(Bm, SEQ_, (t + 1) * 64, Bbuf[c ^ 1], tid);
#pragma unroll
    for (int mf = 0; mf < 4; ++mf) afr[mf] = frag_swz(Ab, wr * 128 + (mf + 4) * 16 + rl, sl, rl);
    __builtin_amdgcn_s_barrier();
    __builtin_amdgcn_s_setprio(1);
#pragma unroll
    for (int mf = 0; mf < 4; ++mf)
#pragma unroll
      for (int nf = 0; nf < 4; ++nf)
        acc[mf + 4][nf] = __builtin_amdgcn_mfma_f32_16x16x32_f16(afr[mf], bfr[nf], acc[mf + 4][nf], 0, 0, 0);
    __builtin_amdgcn_s_setprio(0);
    __builtin_amdgcn_s_barrier();

    // ---- phase 2: read b(kk1), a_lo(kk1); MFMA m0-3 kk1
#pragma unroll
    for (int nf = 0; nf < 4; ++nf) bfr[nf] = frag_swz(Bb, wc * 64 + nf * 16 + rl, 4 + sl, rl);
#pragma unroll
    for (int mf = 0; mf < 4; ++mf) afr[mf] = frag_swz(Ab, wr * 128 + mf * 16 + rl, 4 + sl, rl);
    __builtin_amdgcn_s_barrier();
    __builtin_amdgcn_s_setprio(1);
#pragma unroll
    for (int mf = 0; mf < 4; ++mf)
#pragma unroll
      for (int nf = 0; nf < 4; ++nf)
        acc[mf][nf] = __builtin_amdgcn_mfma_f32_16x16x32_f16(afr[mf], bfr[nf], acc[mf][nf], 0, 0, 0);
    __builtin_amdgcn_s_setprio(0);
    __builtin_amdgcn_s_barrier();

    // ---- phase 3: read a_hi(kk1); MFMA m4-7 kk1
#pragma unroll
    for (int mf = 0; mf < 4; ++mf) afr[mf] = frag_swz(Ab, wr * 128 + (mf + 4) * 16 + rl, 4 + sl, rl);
    __builtin_amdgcn_s_setprio(1);
#pragma unroll
    for (int mf = 0; mf < 4; ++mf)
#pragma unroll
      for (int nf = 0; nf < 4; ++nf)
        acc[mf + 4][nf] = __builtin_amdgcn_mfma_f32_16x16x32_f16(afr[mf], bfr[nf], acc[mf + 4][nf], 0, 0, 0);
    __builtin_amdgcn_s_setprio(0);

    // ---- tile boundary: full drain + fence (next tile resident, LDS visible)
    __syncthreads();
  }

  // ---- epilogue: xsum[s',d] = xtok[s',d] + gelu(acc + b2[s'])
#pragma unroll
  for (int mf = 0; mf < 8; ++mf) {
    int rbase = m0 + wr * 128 + mf * 16 + sl * 4;
#pragma unroll
    for (int j = 0; j < 4; ++j) {
      int r = rbase + j;
      float bias = b2[r];
      long rowoff = (long)r * 512;
#pragma unroll
      for (int nf = 0; nf < 4; ++nf) {
        int cc = n0 + wc * 64 + nf * 16 + rl;
        float v = gelu_exact(acc[mf][nf][j] + bias);
        xsb[rowoff + cc] = (f16)((float)xtb[rowoff + cc] + v);
      }
    }
  }
}

// ---- G3 ----
__global__ __launch_bounds__(256) void g3_kernel(const f16* __restrict__ xsum,
    const float* __restrict__ mean, const float* __restrict__ rstd,
    const float* __restrict__ g3, const float* __restrict__ bl3,
    const f16* __restrict__ BT /* = W3T + 512 */, const float* __restrict__ b3,
    f16* __restrict__ xproj) {
  GEMM_PROLOG
  int m0 = blockIdx.y * 128, n0 = blockIdx.x * 128;
  for (int k0 = 0; k0 < 512; k0 += 32) {
    stage_a_ln_f16(xsum, 512, mean, rstd, g3, bl3, m0, k0, As, t);
    stage_gll(BT, 512, n0, k0, Bs, t);
    __syncthreads();
    mfma_step(As, Bs, lane, wr, wc, acc);
    __syncthreads();
  }
#pragma unroll
  for (int mi = 0; mi < 4; ++mi)
#pragma unroll
    for (int ni = 0; ni < 4; ++ni) {
      int c = n0 + wc * 64 + ni * 16 + (lane & 15);
      float bias = b3[c + 1];
      int r0 = m0 + wr * 64 + mi * 16 + (lane >> 4) * 4;
#pragma unroll
      for (int j = 0; j < 4; ++j)
        xproj[(long)(r0 + j) * 512 + c] = (f16)(acc[mi][ni][j] + bias);
    }
}

// ---- score ----
__global__ __launch_bounds__(256) void score_kernel(const f16* __restrict__ xsum,
    const float* __restrict__ mean, const float* __restrict__ rstd,
    const float* __restrict__ g3, const float* __restrict__ bl3,
    const f16* __restrict__ w3c, const float* __restrict__ b3,
    float* __restrict__ xscore) {
  int row = blockIdx.x * 4 + (threadIdx.x >> 6);
  int l = threadIdx.x & 63;
  float m = mean[row], sd = rstd[row];
  half8 h = *(const half8*)(xsum + (long)row * 512 + l * 8);
  half8 wv = *(const half8*)(w3c + l * 8);
  float acc = 0.f;
#pragma unroll
  for (int i = 0; i < 8; ++i) {
    int d = l * 8 + i;
    float v = ((float)h[i] - m) * sd * g3[d] + bl3[d];
    acc += v * (float)wv[i];
  }
#pragma unroll
  for (int off = 32; off > 0; off >>= 1) acc += __shfl_down(acc, off);
  if (l == 0) xscore[row] = acc + b3[0];
}

// ---- diff_topk ----
__global__ __launch_bounds__(256) void topk_kernel(const float* __restrict__ xscore,
                                                   const float* __restrict__ tau,
                                                   f16* __restrict__ Wm) {
  int b = blockIdx.x, t = threadIdx.x;
  __shared__ float red[4];
  float tv = fminf(fmaxf(tau[0], -2.0f), 5.0f);
  float temp = 1.0f / (1.0f + expf(-tv));
  float it = 1.0f / temp;
  float c[8];
  const float* xs = xscore + (size_t)b * SEQ_;
#pragma unroll
  for (int i = 0; i < 8; ++i) c[i] = xs[t * 8 + i];
  for (int k = 0; k < KSEL; ++k) {
    float e[8];
    float p = 0.f;
#pragma unroll
    for (int i = 0; i < 8; ++i) { e[i] = expf(c[i] * it); p += e[i]; }
#pragma unroll
    for (int off = 32; off > 0; off >>= 1) p += __shfl_down(p, off);
    if ((t & 63) == 0) red[t >> 6] = p;
    __syncthreads();
    float S = red[0] + red[1] + red[2] + red[3];
    float iS = 1.0f / S;
    float a[8];
    half8 h;
#pragma unroll
    for (int i = 0; i < 8; ++i) { a[i] = e[i] * iS; h[i] = (f16)a[i]; }
    *(half8*)(Wm + ((size_t)b * KSEL + k) * SEQ_ + t * 8) = h;
#pragma unroll
    for (int i = 0; i < 8; ++i) c[i] += logf(fmaxf(1.0f - a[i], 1e-6f));
    __syncthreads();
  }
}

// ---- GZ (split-K=2) ----
__global__ __launch_bounds__(256) void gz_kernel(const f16* __restrict__ Wm,
    const f16* __restrict__ xprojT, float* __restrict__ Zpart) {
  GEMM_PROLOG
  int b = blockIdx.z, kc = blockIdx.y;
  int n0 = blockIdx.x * 128;
  const f16* A = Wm + (long)b * KSEL * SEQ_;
  const f16* BT = xprojT + (long)b * 512 * SEQ_;
  float* Zb = Zpart + ((long)b * 2 + kc) * KSEL * 512;
  int kbeg = kc * 1024, kend = kbeg + 1024;
  for (int k0 = kbeg; k0 < kend; k0 += 32) {
    stage_gll(A, SEQ_, 0, k0, As, t);
    stage_gll(BT, SEQ_, n0, k0, Bs, t);
    __syncthreads();
    mfma_step(As, Bs, lane, wr, wc, acc);
    __syncthreads();
  }
#pragma unroll
  for (int mi = 0; mi < 4; ++mi)
#pragma unroll
    for (int ni = 0; ni < 4; ++ni) {
      int c = n0 + wc * 64 + ni * 16 + (lane & 15);
      int r0 = wr * 64 + mi * 16 + (lane >> 4) * 4;
#pragma unroll
      for (int j = 0; j < 4; ++j)
        Zb[(long)(r0 + j) * 512 + c] = acc[mi][ni][j];
    }
}

// ---- reduce split-K + transpose -> ZT ----
__global__ __launch_bounds__(256) void ztrans_kernel(const float* __restrict__ Zpart,
                                                     f16* __restrict__ ZT) {
  __shared__ float tile[32][33];
  int b = blockIdx.z;
  int c0 = blockIdx.x * 32, r0 = blockIdx.y * 32;
  int tx = threadIdx.x, ty = threadIdx.y;
  const float* p0 = Zpart + ((long)b * 2 + 0) * KSEL * 512;
  const float* p1 = Zpart + ((long)b * 2 + 1) * KSEL * 512;
#pragma unroll
  for (int i = 0; i < 4; ++i) {
    int r = r0 + ty + i * 8, c = c0 + tx;
    tile[ty + i * 8][tx] = p0[(long)r * 512 + c] + p1[(long)r * 512 + c];
  }
  __syncthreads();
  f16* d = ZT + (long)b * 512 * KSEL;
#pragma unroll
  for (int i = 0; i < 4; ++i) {
    int c = c0 + ty + i * 8, r = r0 + tx;
    d[(long)c * KSEL + r] = (f16)tile[tx][ty + i * 8];
  }
}

// ---- GY ----
__global__ __launch_bounds__(256) void gy_kernel(const f16* __restrict__ WmT,
    const f16* __restrict__ ZT, const f16* __restrict__ xproj,
    f16* __restrict__ rbuf) {
  GEMM_PROLOG
  int b = blockIdx.z;
  int m0 = blockIdx.y * 128, n0 = blockIdx.x * 128;
  const f16* A = WmT + (long)b * SEQ_ * KSEL;
  const f16* BT = ZT + (long)b * 512 * KSEL;
  const f16* xpb = xproj + (long)b * SEQ_ * 512;
  f16* rb = rbuf + (long)b * SEQ_ * 512;
  for (int k0 = 0; k0 < KSEL; k0 += 32) {
    stage_gll(A, KSEL, m0, k0, As, t);
    stage_gll(BT, KSEL, n0, k0, Bs, t);
    __syncthreads();
    mfma_step(As, Bs, lane, wr, wc, acc);
    __syncthreads();
  }
#pragma unroll
  for (int mi = 0; mi < 4; ++mi)
#pragma unroll
    for (int ni = 0; ni < 4; ++ni) {
      int c = n0 + wc * 64 + ni * 16 + (lane & 15);
      int r0 = m0 + wr * 64 + mi * 16 + (lane >> 4) * 4;
#pragma unroll
      for (int j = 0; j < 4; ++j) {
        long idx = (long)(r0 + j) * 512 + c;
        rb[idx] = (f16)((float)xpb[idx] + acc[mi][ni][j]);
      }
    }
}

// ---- G4 ----
__global__ __launch_bounds__(256) void g4_kernel(const f16* __restrict__ rbuf,
    const float* __restrict__ mean, const float* __restrict__ rstd,
    const float* __restrict__ g4, const float* __restrict__ bl4,
    const f16* __restrict__ W4T, const float* __restrict__ b4,
    float* __restrict__ out) {
  GEMM_PROLOG
  int m0 = blockIdx.y * 128, n0 = blockIdx.x * 128;
  for (int k0 = 0; k0 < 512; k0 += 32) {
    stage_a_ln_f16(rbuf, 512, mean, rstd, g4, bl4, m0, k0, As, t);
    stage_gll(W4T, 512, n0, k0, Bs, t);
    __syncthreads();
    mfma_step(As, Bs, lane, wr, wc, acc);
    __syncthreads();
  }
#pragma unroll
  for (int mi = 0; mi < 4; ++mi)
#pragma unroll
    for (int ni = 0; ni < 4; ++ni) {
      int c = n0 + wc * 64 + ni * 16 + (lane & 15);
      float bias = b4[c];
      int r0 = m0 + wr * 64 + mi * 16 + (lane >> 4) * 4;
#pragma unroll
      for (int j = 0; j < 4; ++j)
        out[(long)(r0 + j) * 512 + c] = acc[mi][ni][j] + bias;
    }
}

// ======================= launcher =======================
extern "C" void kernel_launch(void* const* d_in, const int* in_sizes, int n_in,
                              void* d_out, int out_size, void* d_ws, size_t ws_size,
                              hipStream_t stream) {
  const float* x    = (const float*)d_in[0];
  const float* tau  = (const float*)d_in[1];
  const float* g1   = (const float*)d_in[2];
  const float* bl1  = (const float*)d_in[3];
  const float* W1   = (const float*)d_in[4];
  const float* b1   = (const float*)d_in[5];
  const float* g2   = (const float*)d_in[6];
  const float* bl2  = (const float*)d_in[7];
  const float* W2   = (const float*)d_in[8];
  const float* b2   = (const float*)d_in[9];
  const float* g3   = (const float*)d_in[10];
  const float* bl3  = (const float*)d_in[11];
  const float* W3   = (const float*)d_in[12];
  const float* b3   = (const float*)d_in[13];
  const float* g4   = (const float*)d_in[14];
  const float* bl4  = (const float*)d_in[15];
  const float* W4   = (const float*)d_in[16];
  const float* b4   = (const float*)d_in[17];
  float* out = (float*)d_out;

  const long NTOK = (long)B_ * SEQ_;  // 65536

  // ---- workspace layout ----
  char* ws = (char*)d_ws;
  f16* regA   = (f16*)(ws);                         // 64MB: A2, later xproj
  f16* regB   = (f16*)(ws + (64l << 20));           // 64MB: xsum, later rbuf
  float* Zpart = (float*)(ws + (128l << 20));       // 16MB (split-K=2 fp32)
  f16* W2T    = (f16*)(ws + (144l << 20));          // 8MB
  f16* W1T    = (f16*)(ws + (152l << 20));          // 0.5MB
  f16* W3T    = (f16*)(ws + (153l << 20));          // 0.51MB
  f16* W4T    = (f16*)(ws + (154l << 20));          // 0.5MB
  float* xscore = (float*)(ws + (155l << 20));      // 0.25MB
  float* meanA  = (float*)(ws + (156l << 20));      // 0.25MB
  float* rstdA  = meanA + NTOK;                     // 0.25MB
  float* mean2  = rstdA + NTOK;                     // 64KB
  float* rstd2  = mean2 + B_ * 512;                 // 64KB
  float2* part  = (float2*)(rstd2 + B_ * 512);      // 1MB
  f16* ZT     = (f16*)(ws + (157l << 20));          // 4MB

  // ---- d_out (128MB) doubles as scratch, fully overwritten by G4 ----
  f16* xtok   = (f16*)d_out;                               // [0,64) until g2 reads it
  f16* xprojT = (f16*)d_out;                               // [0,64) written step 5 (xtok dead)
  f16* Wm     = (f16*)((char*)d_out + (64l << 20));        // [64,80)
  f16* WmT    = (f16*)((char*)d_out + (80l << 20));        // [80,96)

  f16* A2    = regA;
  f16* xsum  = regB;
  f16* xproj = regA;   // A2 dead after G2
  f16* rbuf  = regB;   // xsum dead after G3

  dim3 tb(32, 8);

  // weight transposes (f16, [n][k])
  transpose_cvt<float><<<dim3(16, 16, 1), tb, 0, stream>>>(W1, W1T, 512, 512, 0, 0);
  transpose_cvt<float><<<dim3(64, 64, 1), tb, 0, stream>>>(W2, W2T, 2048, 2048, 0, 0);
  transpose_cvt<float><<<dim3(17, 16, 1), tb, 0, stream>>>(W3, W3T, 512, 513, 0, 0);
  transpose_cvt<float><<<dim3(16, 16, 1), tb, 0, stream>>>(W4, W4T, 512, 512, 0, 0);

  // 1) LN1 stats + G1 -> xtok (f16, in d_out)
  rowstats512<<<NTOK / 4, 256, 0, stream>>>(x, meanA, rstdA);
  g1_kernel<<<dim3(4, 512), 256, 0, stream>>>(x, meanA, rstdA, g1, bl1, W1T, b1, xtok);

  // 2) LN2 stats + transposed normalize -> A2, then G2 (256x256 8-phase) -> xsum
  colstats_part<<<B_ * 8, 512, 0, stream>>>(xtok, part);
  colstats_fin<<<64, 256, 0, stream>>>(part, mean2, rstd2);
  trans2_kernel<<<dim3(16, 64, B_), tb, 0, stream>>>(xtok, mean2, rstd2, g2, bl2, A2);
  g2_8p<<<dim3(2, 8, B_), 512, 0, stream>>>(W2T, A2, b2, xtok, xsum);

  // 3) LN3 stats, score column, G3 -> xproj (overwrites A2; xtok now dead)
  rowstats512_f16<<<NTOK / 4, 256, 0, stream>>>(xsum, meanA, rstdA);
  score_kernel<<<NTOK / 4, 256, 0, stream>>>(xsum, meanA, rstdA, g3, bl3, W3T, b3, xscore);
  g3_kernel<<<dim3(4, 512), 256, 0, stream>>>(xsum, meanA, rstdA, g3, bl3, W3T + 512, b3, xproj);

  // 4) top-k -> Wm (f16, d_out[64,80))
  topk_kernel<<<B_, 256, 0, stream>>>(xscore, tau, Wm);

  // 5) transposes for GZ/GY operands (xprojT overwrites dead xtok region)
  transpose_cvt<f16><<<dim3(16, 64, B_), tb, 0, stream>>>(xproj, xprojT, 2048, 512,
      (long)SEQ_ * 512, (long)512 * SEQ_);
  transpose_cvt<f16><<<dim3(64, 4, B_), tb, 0, stream>>>(Wm, WmT, 128, 2048,
      (long)KSEL * SEQ_, (long)SEQ_ * KSEL);

  // 6) Z = Wm @ xproj (split-K=2), then reduce+transpose -> ZT
  gz_kernel<<<dim3(4, 2, B_), 256, 0, stream>>>(Wm, xprojT, Zpart);
  ztrans_kernel<<<dim3(16, 4, B_), tb, 0, stream>>>(Zpart, ZT);

  // 7) rbuf = xproj + Wm^T @ Z (overwrites xsum)
  gy_kernel<<<dim3(4, 16, B_), 256, 0, stream>>>(WmT, ZT, xproj, rbuf);

  // 8) LN4 stats + G4 -> out (overwrites all d_out scratch)
  rowstats512_f16<<<NTOK / 4, 256, 0, stream>>>(rbuf, meanA, rstdA);
  g4_kernel<<<dim3(4, 512), 256, 0, stream>>>(rbuf, meanA, rstdA, g4, bl4, W4T, b4, out);
}

// Round 6
// 887.254 us; speedup vs baseline: 1.0021x; 1.0021x over previous
//
#include <hip/hip_runtime.h>
#include <math.h>

#define B_   32
#define SEQ_ 2048
#define DIM_ 512
#define KSEL 128

typedef _Float16 f16;
typedef _Float16 half8 __attribute__((ext_vector_type(8)));
typedef float floatx4 __attribute__((ext_vector_type(4)));

#define LSTR2 32   // linear LDS row stride in halves (64B rows) for gll staging

__device__ __forceinline__ float gelu_exact(float v) {
  return 0.5f * v * (1.0f + erff(v * 0.70710678118654752440f));
}

// ======================= stats kernels =======================
__global__ __launch_bounds__(256) void rowstats512(const float* __restrict__ X,
                                                   float* __restrict__ mean,
                                                   float* __restrict__ rstd) {
  int row = blockIdx.x * 4 + (threadIdx.x >> 6);
  int l = threadIdx.x & 63;
  const float4* p = (const float4*)(X + (size_t)row * 512);
  float4 v0 = p[l * 2], v1 = p[l * 2 + 1];
  float s = v0.x + v0.y + v0.z + v0.w + v1.x + v1.y + v1.z + v1.w;
  float q = v0.x*v0.x + v0.y*v0.y + v0.z*v0.z + v0.w*v0.w
          + v1.x*v1.x + v1.y*v1.y + v1.z*v1.z + v1.w*v1.w;
#pragma unroll
  for (int off = 32; off > 0; off >>= 1) {
    s += __shfl_down(s, off);
    q += __shfl_down(q, off);
  }
  if (l == 0) {
    float m = s * (1.0f / 512.0f);
    float var = q * (1.0f / 512.0f) - m * m;
    mean[row] = m;
    rstd[row] = rsqrtf(var + 1e-5f);
  }
}

__global__ __launch_bounds__(256) void rowstats512_f16(const f16* __restrict__ X,
                                                       float* __restrict__ mean,
                                                       float* __restrict__ rstd) {
  int row = blockIdx.x * 4 + (threadIdx.x >> 6);
  int l = threadIdx.x & 63;
  half8 h = *(const half8*)(X + (size_t)row * 512 + l * 8);
  float s = 0.f, q = 0.f;
#pragma unroll
  for (int i = 0; i < 8; ++i) { float v = (float)h[i]; s += v; q += v * v; }
#pragma unroll
  for (int off = 32; off > 0; off >>= 1) {
    s += __shfl_down(s, off);
    q += __shfl_down(q, off);
  }
  if (l == 0) {
    float m = s * (1.0f / 512.0f);
    float var = q * (1.0f / 512.0f) - m * m;
    mean[row] = m;
    rstd[row] = rsqrtf(var + 1e-5f);
  }
}

__global__ __launch_bounds__(512) void colstats_part(const f16* __restrict__ xtok,
                                                     float2* __restrict__ part) {
  int b = blockIdx.x >> 3, pr = blockIdx.x & 7;
  int d = threadIdx.x;
  const f16* src = xtok + ((size_t)b * SEQ_ + (size_t)pr * 256) * 512 + d;
  float s = 0.f, q = 0.f;
#pragma unroll 4
  for (int i = 0; i < 256; ++i) {
    float v = (float)src[(size_t)i * 512];
    s += v; q += v * v;
  }
  part[(size_t)blockIdx.x * 512 + d] = make_float2(s, q);
}

__global__ __launch_bounds__(256) void colstats_fin(const float2* __restrict__ part,
                                                    float* __restrict__ mean,
                                                    float* __restrict__ rstd) {
  int idx = blockIdx.x * 256 + threadIdx.x;
  int b = idx >> 9;
  float s = 0.f, q = 0.f;
#pragma unroll
  for (int p = 0; p < 8; ++p) {
    float2 v = part[((size_t)(b * 8 + p)) * 512 + (idx & 511)];
    s += v.x; q += v.y;
  }
  float m = s * (1.0f / 2048.0f);
  mean[idx] = m;
  rstd[idx] = rsqrtf(q * (1.0f / 2048.0f) - m * m + 1e-5f);
}

// ======================= transpose / convert =======================
template <typename T>
__global__ __launch_bounds__(256) void transpose_cvt(const T* __restrict__ src,
                                                     f16* __restrict__ dst,
                                                     int R, int C, long sb, long db) {
  __shared__ float tile[32][33];
  const T* s = src + (long)blockIdx.z * sb;
  f16* d = dst + (long)blockIdx.z * db;
  int c0 = blockIdx.x * 32, r0 = blockIdx.y * 32;
  int tx = threadIdx.x, ty = threadIdx.y;
#pragma unroll
  for (int i = 0; i < 4; ++i) {
    int r = r0 + ty + i * 8, c = c0 + tx;
    if (r < R && c < C) tile[ty + i * 8][tx] = (float)s[(long)r * C + c];
  }
  __syncthreads();
#pragma unroll
  for (int i = 0; i < 4; ++i) {
    int c = c0 + ty + i * 8, r = r0 + tx;
    if (c < C && r < R) d[(long)c * R + r] = (f16)tile[tx][ty + i * 8];
  }
}

// LN2-apply + transpose: A2[b][d][s] = (xtok[b][s][d]-m2[b,d])*r2[b,d]*g2[s]+bl2[s]
__global__ __launch_bounds__(256) void trans2_kernel(const f16* __restrict__ xtok,
    const float* __restrict__ mean2, const float* __restrict__ rstd2,
    const float* __restrict__ g2, const float* __restrict__ bl2,
    f16* __restrict__ A2) {
  __shared__ float tile[32][33];
  int b = blockIdx.z;
  const f16* src = xtok + (long)b * SEQ_ * 512;
  f16* dst = A2 + (long)b * 512 * SEQ_;
  int d0 = blockIdx.x * 32, s0 = blockIdx.y * 32;
  int tx = threadIdx.x, ty = threadIdx.y;
  float m = mean2[b * 512 + d0 + tx];
  float rs = rstd2[b * 512 + d0 + tx];
#pragma unroll
  for (int i = 0; i < 4; ++i) {
    int s = s0 + ty + i * 8;
    float v = (float)src[(long)s * 512 + d0 + tx];
    tile[ty + i * 8][tx] = (v - m) * rs * g2[s] + bl2[s];
  }
  __syncthreads();
#pragma unroll
  for (int i = 0; i < 4; ++i) {
    int d = d0 + ty + i * 8, s = s0 + tx;
    dst[(long)d * SEQ_ + s] = (f16)tile[tx][ty + i * 8];
  }
}

// ======================= 128-tile GEMM core (m97 structure) =======================
__device__ __forceinline__ void stage_gll(const f16* __restrict__ src, long ld,
                                          int row0, int k0, f16* S, int t) {
  int w = t >> 6, lane = t & 63;
  int r = lane >> 2, c8 = (lane & 3) * 8;
#pragma unroll
  for (int i = 0; i < 2; ++i) {
    int chunk = w * 2 + i;
    const f16* g = src + (long)(row0 + chunk * 16 + r) * ld + k0 + c8;
    f16* l = S + chunk * 16 * LSTR2;
    __builtin_amdgcn_global_load_lds(
        (const __attribute__((address_space(1))) void*)g,
        (__attribute__((address_space(3))) void*)l, 16, 0, 0);
  }
}

__device__ __forceinline__ void stage_a_ln_f32(const float* __restrict__ src, long ld,
    const float* __restrict__ mean, const float* __restrict__ rstd,
    const float* __restrict__ g, const float* __restrict__ bl,
    int row0, int k0, f16* S, int t) {
  int row = t >> 1, kc = (t & 1) * 16;
  int r = row0 + row, c = k0 + kc;
  float m = mean[r], sd = rstd[r];
  const float* p = src + (long)r * ld + c;
  float v[16], gv[16], bv[16];
#pragma unroll
  for (int i = 0; i < 4; ++i) {
    float4 q = ((const float4*)p)[i];
    v[i*4+0]=q.x; v[i*4+1]=q.y; v[i*4+2]=q.z; v[i*4+3]=q.w;
    float4 gq = ((const float4*)(g + c))[i];
    gv[i*4+0]=gq.x; gv[i*4+1]=gq.y; gv[i*4+2]=gq.z; gv[i*4+3]=gq.w;
    float4 bq = ((const float4*)(bl + c))[i];
    bv[i*4+0]=bq.x; bv[i*4+1]=bq.y; bv[i*4+2]=bq.z; bv[i*4+3]=bq.w;
  }
  half8 o0, o1;
#pragma unroll
  for (int i = 0; i < 8; ++i) {
    o0[i] = (f16)((v[i] - m) * sd * gv[i] + bv[i]);
    o1[i] = (f16)((v[i + 8] - m) * sd * gv[i + 8] + bv[i + 8]);
  }
  *(half8*)(S + row * LSTR2 + kc) = o0;
  *(half8*)(S + row * LSTR2 + kc + 8) = o1;
}

__device__ __forceinline__ void stage_a_ln_f16(const f16* __restrict__ src, long ld,
    const float* __restrict__ mean, const float* __restrict__ rstd,
    const float* __restrict__ g, const float* __restrict__ bl,
    int row0, int k0, f16* S, int t) {
  int row = t >> 1, kc = (t & 1) * 16;
  int r = row0 + row, c = k0 + kc;
  float m = mean[r], sd = rstd[r];
  const f16* p = src + (long)r * ld + c;
  half8 h0 = *(const half8*)(p);
  half8 h1 = *(const half8*)(p + 8);
  float gv[16], bv[16];
#pragma unroll
  for (int i = 0; i < 4; ++i) {
    float4 gq = ((const float4*)(g + c))[i];
    gv[i*4+0]=gq.x; gv[i*4+1]=gq.y; gv[i*4+2]=gq.z; gv[i*4+3]=gq.w;
    float4 bq = ((const float4*)(bl + c))[i];
    bv[i*4+0]=bq.x; bv[i*4+1]=bq.y; bv[i*4+2]=bq.z; bv[i*4+3]=bq.w;
  }
  half8 o0, o1;
#pragma unroll
  for (int i = 0; i < 8; ++i) {
    o0[i] = (f16)(((float)h0[i] - m) * sd * gv[i] + bv[i]);
    o1[i] = (f16)(((float)h1[i] - m) * sd * gv[i + 8] + bv[i + 8]);
  }
  *(half8*)(S + row * LSTR2 + kc) = o0;
  *(half8*)(S + row * LSTR2 + kc + 8) = o1;
}

__device__ __forceinline__ void mfma_step(const f16* As, const f16* Bs, int lane,
                                          int wr, int wc, floatx4 acc[4][4]) {
  int kc = (lane >> 4) * 8;
  int rl = lane & 15;
  half8 a[4], b[4];
#pragma unroll
  for (int mi = 0; mi < 4; ++mi)
    a[mi] = *(const half8*)(As + (wr * 64 + mi * 16 + rl) * LSTR2 + kc);
#pragma unroll
  for (int ni = 0; ni < 4; ++ni)
    b[ni] = *(const half8*)(Bs + (wc * 64 + ni * 16 + rl) * LSTR2 + kc);
#pragma unroll
  for (int mi = 0; mi < 4; ++mi)
#pragma unroll
    for (int ni = 0; ni < 4; ++ni)
      acc[mi][ni] = __builtin_amdgcn_mfma_f32_16x16x32_f16(a[mi], b[ni], acc[mi][ni], 0, 0, 0);
}

#define GEMM_PROLOG \
  __shared__ __attribute__((aligned(16))) f16 As[128 * LSTR2]; \
  __shared__ __attribute__((aligned(16))) f16 Bs[128 * LSTR2]; \
  int t = threadIdx.x; \
  int lane = t & 63, w = t >> 6, wr = w >> 1, wc = w & 1; \
  floatx4 acc[4][4]; \
  _Pragma("unroll") for (int mi = 0; mi < 4; ++mi) \
  _Pragma("unroll") for (int ni = 0; ni < 4; ++ni) acc[mi][ni] = (floatx4){0.f,0.f,0.f,0.f};

// ---- G1 ----
__global__ __launch_bounds__(256) void g1_kernel(const float* __restrict__ x,
    const float* __restrict__ mean, const float* __restrict__ rstd,
    const float* __restrict__ g1, const float* __restrict__ bl1,
    const f16* __restrict__ W1T, const float* __restrict__ b1,
    f16* __restrict__ xtok) {
  GEMM_PROLOG
  int m0 = blockIdx.y * 128, n0 = blockIdx.x * 128;
  for (int k0 = 0; k0 < 512; k0 += 32) {
    stage_a_ln_f32(x, 512, mean, rstd, g1, bl1, m0, k0, As, t);
    stage_gll(W1T, 512, n0, k0, Bs, t);
    __syncthreads();
    mfma_step(As, Bs, lane, wr, wc, acc);
    __syncthreads();
  }
#pragma unroll
  for (int mi = 0; mi < 4; ++mi)
#pragma unroll
    for (int ni = 0; ni < 4; ++ni) {
      int c = n0 + wc * 64 + ni * 16 + (lane & 15);
      float bias = b1[c];
      int r0 = m0 + wr * 64 + mi * 16 + (lane >> 4) * 4;
#pragma unroll
      for (int j = 0; j < 4; ++j)
        xtok[(long)(r0 + j) * 512 + c] = (f16)gelu_exact(acc[mi][ni][j] + bias);
    }
}

// ======================= G2: 256x256 BK64 deep-pipelined engine =======================
// M = s' (2048, rows of W2T), N = d (512, rows of A2), K = s (2048).
// 8 waves (2M x 4N), per-wave 128x64 out. 2 LDS buffers, T2 swizzle, T5 setprio.
__device__ __forceinline__ void stage_tile256(const f16* __restrict__ srcbase, long ld,
                                              int k0, f16* dst, int tid) {
  int w = tid >> 6, l = tid & 63;
  int colh = ((l & 7) ^ (l >> 3)) << 3;   // pre-swizzled source column (halves)
  int rsub = w * 8 + (l >> 3);
#pragma unroll
  for (int q = 0; q < 4; ++q) {
    const f16* g = srcbase + (long)(q * 64 + rsub) * ld + k0 + colh;
    f16* lp = dst + (long)(q * 512 + w * 64) * 8;  // wave-uniform; HW adds lane*16B
    __builtin_amdgcn_global_load_lds(
        (const __attribute__((address_space(1))) void*)g,
        (__attribute__((address_space(3))) void*)lp, 16, 0, 0);
  }
}

__device__ __forceinline__ half8 frag_swz(const f16* buf, int row, int kslot, int rl) {
  // LDS rows are 64 halves (128B); swizzle: slot' = kslot ^ (row&7), row&7 == rl&7 here
  return *(const half8*)(buf + (long)row * 64 + (((kslot ^ (rl & 7))) << 3));
}

__global__ __launch_bounds__(512, 2) void g2_8p(const f16* __restrict__ W2T,
    const f16* __restrict__ A2, const float* __restrict__ b2,
    const f16* __restrict__ xtok, f16* __restrict__ xsum) {
  __shared__ __attribute__((aligned(16))) f16 Abuf[2][256 * 64];
  __shared__ __attribute__((aligned(16))) f16 Bbuf[2][256 * 64];
  int tid = threadIdx.x;
  int l = tid & 63, w = tid >> 6;
  int wr = w >> 2, wc = w & 3;          // 2M x 4N wave grid
  int rl = l & 15, sl = l >> 4;         // fragment lane coords
  int b = blockIdx.z;
  int m0 = blockIdx.y * 256;            // s' base
  int n0 = blockIdx.x * 256;            // d base
  const f16* Am = W2T + (long)m0 * SEQ_;
  const f16* Bm = A2 + (long)b * 512 * SEQ_ + (long)n0 * SEQ_;
  const f16* xtb = xtok + (long)b * SEQ_ * 512;
  f16* xsb = xsum + (long)b * SEQ_ * 512;

  floatx4 acc[8][4];
#pragma unroll
  for (int mf = 0; mf < 8; ++mf)
#pragma unroll
    for (int nf = 0; nf < 4; ++nf) acc[mf][nf] = (floatx4){0.f, 0.f, 0.f, 0.f};

  const int NT = SEQ_ / 64;  // 32 K-tiles
  // prologue: stage tile 0
  stage_tile256(Am, SEQ_, 0, Abuf[0], tid);
  stage_tile256(Bm, SEQ_, 0, Bbuf[0], tid);
  __syncthreads();   // drains vmcnt(0): tile 0 resident

  for (int t = 0; t < NT; ++t) {
    int c = t & 1;
    const f16* Ab = Abuf[c];
    const f16* Bb = Bbuf[c];
    half8 afr[4], bfr[4];

    // ---- phase 0: stage A(t+1); read b(kk0), a_lo(kk0); MFMA m0-3 kk0
    if (t + 1 < NT) stage_tile256(Am, SEQ_, (t + 1) * 64, Abuf[c ^ 1], tid);
#pragma unroll
    for (int nf = 0; nf < 4; ++nf) bfr[nf] = frag_swz(Bb, wc * 64 + nf * 16 + rl, sl, rl);
#pragma unroll
    for (int mf = 0; mf < 4; ++mf) afr[mf] = frag_swz(Ab, wr * 128 + mf * 16 + rl, sl, rl);
    __builtin_amdgcn_s_barrier();
    __builtin_amdgcn_s_setprio(1);
#pragma unroll
    for (int mf = 0; mf < 4; ++mf)
#pragma unroll
      for (int nf = 0; nf < 4; ++nf)
        acc[mf][nf] = __builtin_amdgcn_mfma_f32_16x16x32_f16(afr[mf], bfr[nf], acc[mf][nf], 0, 0, 0);
    __builtin_amdgcn_s_setprio(0);
    __builtin_amdgcn_s_barrier();

    // ---- phase 1: stage B(t+1); read a_hi(kk0); MFMA m4-7 kk0
    if (t + 1 < NT) stage_tile256(Bm, SEQ_, (t + 1) * 64, Bbuf[c ^ 1], tid);
#pragma unroll
    for (int mf = 0; mf < 4; ++mf) afr[mf] = frag_swz(Ab, wr * 128 + (mf + 4) * 16 + rl, sl, rl);
    __builtin_amdgcn_s_barrier();
    __builtin_amdgcn_s_setprio(1);
#pragma unroll
    for (int mf = 0; mf < 4; ++mf)
#pragma unroll
      for (int nf = 0; nf < 4; ++nf)
        acc[mf + 4][nf] = __builtin_amdgcn_mfma_f32_16x16x32_f16(afr[mf], bfr[nf], acc[mf + 4][nf], 0, 0, 0);
    __builtin_amdgcn_s_setprio(0);
    __builtin_amdgcn_s_barrier();

    // ---- phase 2: read b(kk1), a_lo(kk1); MFMA m0-3 kk1
#pragma unroll
    for (int nf = 0; nf < 4; ++nf) bfr[nf] = frag_swz(Bb, wc * 64 + nf * 16 + rl, 4 + sl, rl);
#pragma unroll
    for (int mf = 0; mf < 4; ++mf) afr[mf] = frag_swz(Ab, wr * 128 + mf * 16 + rl, 4 + sl, rl);
    __builtin_amdgcn_s_barrier();
    __builtin_amdgcn_s_setprio(1);
#pragma unroll
    for (int mf = 0; mf < 4; ++mf)
#pragma unroll
      for (int nf = 0; nf < 4; ++nf)
        acc[mf][nf] = __builtin_amdgcn_mfma_f32_16x16x32_f16(afr[mf], bfr[nf], acc[mf][nf], 0, 0, 0);
    __builtin_amdgcn_s_setprio(0);
    __builtin_amdgcn_s_barrier();

    // ---- phase 3: read a_hi(kk1); MFMA m4-7 kk1
#pragma unroll
    for (int mf = 0; mf < 4; ++mf) afr[mf] = frag_swz(Ab, wr * 128 + (mf + 4) * 16 + rl, 4 + sl, rl);
    __builtin_amdgcn_s_setprio(1);
#pragma unroll
    for (int mf = 0; mf < 4; ++mf)
#pragma unroll
      for (int nf = 0; nf < 4; ++nf)
        acc[mf + 4][nf] = __builtin_amdgcn_mfma_f32_16x16x32_f16(afr[mf], bfr[nf], acc[mf + 4][nf], 0, 0, 0);
    __builtin_amdgcn_s_setprio(0);

    // ---- tile boundary: full drain + fence (next tile resident, LDS visible)
    __syncthreads();
  }

  // ---- epilogue: xsum[s',d] = xtok[s',d] + gelu(acc + b2[s'])
#pragma unroll
  for (int mf = 0; mf < 8; ++mf) {
    int rbase = m0 + wr * 128 + mf * 16 + sl * 4;
#pragma unroll
    for (int j = 0; j < 4; ++j) {
      int r = rbase + j;
      float bias = b2[r];
      long rowoff = (long)r * 512;
#pragma unroll
      for (int nf = 0; nf < 4; ++nf) {
        int cc = n0 + wc * 64 + nf * 16 + rl;
        float v = gelu_exact(acc[mf][nf][j] + bias);
        xsb[rowoff + cc] = (f16)((float)xtb[rowoff + cc] + v);
      }
    }
  }
}

// ---- G3 ----
__global__ __launch_bounds__(256) void g3_kernel(const f16* __restrict__ xsum,
    const float* __restrict__ mean, const float* __restrict__ rstd,
    const float* __restrict__ g3, const float* __restrict__ bl3,
    const f16* __restrict__ BT /* = W3T + 512 */, const float* __restrict__ b3,
    f16* __restrict__ xproj) {
  GEMM_PROLOG
  int m0 = blockIdx.y * 128, n0 = blockIdx.x * 128;
  for (int k0 = 0; k0 < 512; k0 += 32) {
    stage_a_ln_f16(xsum, 512, mean, rstd, g3, bl3, m0, k0, As, t);
    stage_gll(BT, 512, n0, k0, Bs, t);
    __syncthreads();
    mfma_step(As, Bs, lane, wr, wc, acc);
    __syncthreads();
  }
#pragma unroll
  for (int mi = 0; mi < 4; ++mi)
#pragma unroll
    for (int ni = 0; ni < 4; ++ni) {
      int c = n0 + wc * 64 + ni * 16 + (lane & 15);
      float bias = b3[c + 1];
      int r0 = m0 + wr * 64 + mi * 16 + (lane >> 4) * 4;
#pragma unroll
      for (int j = 0; j < 4; ++j)
        xproj[(long)(r0 + j) * 512 + c] = (f16)(acc[mi][ni][j] + bias);
    }
}

// ---- score ----
__global__ __launch_bounds__(256) void score_kernel(const f16* __restrict__ xsum,
    const float* __restrict__ mean, const float* __restrict__ rstd,
    const float* __restrict__ g3, const float* __restrict__ bl3,
    const f16* __restrict__ w3c, const float* __restrict__ b3,
    float* __restrict__ xscore) {
  int row = blockIdx.x * 4 + (threadIdx.x >> 6);
  int l = threadIdx.x & 63;
  float m = mean[row], sd = rstd[row];
  half8 h = *(const half8*)(xsum + (long)row * 512 + l * 8);
  half8 wv = *(const half8*)(w3c + l * 8);
  float acc = 0.f;
#pragma unroll
  for (int i = 0; i < 8; ++i) {
    int d = l * 8 + i;
    float v = ((float)h[i] - m) * sd * g3[d] + bl3[d];
    acc += v * (float)wv[i];
  }
#pragma unroll
  for (int off = 32; off > 0; off >>= 1) acc += __shfl_down(acc, off);
  if (l == 0) xscore[row] = acc + b3[0];
}

// ---- diff_topk ----
__global__ __launch_bounds__(256) void topk_kernel(const float* __restrict__ xscore,
                                                   const float* __restrict__ tau,
                                                   f16* __restrict__ Wm) {
  int b = blockIdx.x, t = threadIdx.x;
  __shared__ float red[4];
  float tv = fminf(fmaxf(tau[0], -2.0f), 5.0f);
  float temp = 1.0f / (1.0f + expf(-tv));
  float it = 1.0f / temp;
  float c[8];
  const float* xs = xscore + (size_t)b * SEQ_;
#pragma unroll
  for (int i = 0; i < 8; ++i) c[i] = xs[t * 8 + i];
  for (int k = 0; k < KSEL; ++k) {
    float e[8];
    float p = 0.f;
#pragma unroll
    for (int i = 0; i < 8; ++i) { e[i] = expf(c[i] * it); p += e[i]; }
#pragma unroll
    for (int off = 32; off > 0; off >>= 1) p += __shfl_down(p, off);
    if ((t & 63) == 0) red[t >> 6] = p;
    __syncthreads();
    float S = red[0] + red[1] + red[2] + red[3];
    float iS = 1.0f / S;
    float a[8];
    half8 h;
#pragma unroll
    for (int i = 0; i < 8; ++i) { a[i] = e[i] * iS; h[i] = (f16)a[i]; }
    *(half8*)(Wm + ((size_t)b * KSEL + k) * SEQ_ + t * 8) = h;
#pragma unroll
    for (int i = 0; i < 8; ++i) c[i] += logf(fmaxf(1.0f - a[i], 1e-6f));
    __syncthreads();
  }
}

// ---- GZ (split-K=2) ----
__global__ __launch_bounds__(256) void gz_kernel(const f16* __restrict__ Wm,
    const f16* __restrict__ xprojT, float* __restrict__ Zpart) {
  GEMM_PROLOG
  int b = blockIdx.z, kc = blockIdx.y;
  int n0 = blockIdx.x * 128;
  const f16* A = Wm + (long)b * KSEL * SEQ_;
  const f16* BT = xprojT + (long)b * 512 * SEQ_;
  float* Zb = Zpart + ((long)b * 2 + kc) * KSEL * 512;
  int kbeg = kc * 1024, kend = kbeg + 1024;
  for (int k0 = kbeg; k0 < kend; k0 += 32) {
    stage_gll(A, SEQ_, 0, k0, As, t);
    stage_gll(BT, SEQ_, n0, k0, Bs, t);
    __syncthreads();
    mfma_step(As, Bs, lane, wr, wc, acc);
    __syncthreads();
  }
#pragma unroll
  for (int mi = 0; mi < 4; ++mi)
#pragma unroll
    for (int ni = 0; ni < 4; ++ni) {
      int c = n0 + wc * 64 + ni * 16 + (lane & 15);
      int r0 = wr * 64 + mi * 16 + (lane >> 4) * 4;
#pragma unroll
      for (int j = 0; j < 4; ++j)
        Zb[(long)(r0 + j) * 512 + c] = acc[mi][ni][j];
    }
}

// ---- reduce split-K + transpose -> ZT ----
__global__ __launch_bounds__(256) void ztrans_kernel(const float* __restrict__ Zpart,
                                                     f16* __restrict__ ZT) {
  __shared__ float tile[32][33];
  int b = blockIdx.z;
  int c0 = blockIdx.x * 32, r0 = blockIdx.y * 32;
  int tx = threadIdx.x, ty = threadIdx.y;
  const float* p0 = Zpart + ((long)b * 2 + 0) * KSEL * 512;
  const float* p1 = Zpart + ((long)b * 2 + 1) * KSEL * 512;
#pragma unroll
  for (int i = 0; i < 4; ++i) {
    int r = r0 + ty + i * 8, c = c0 + tx;
    tile[ty + i * 8][tx] = p0[(long)r * 512 + c] + p1[(long)r * 512 + c];
  }
  __syncthreads();
  f16* d = ZT + (long)b * 512 * KSEL;
#pragma unroll
  for (int i = 0; i < 4; ++i) {
    int c = c0 + ty + i * 8, r = r0 + tx;
    d[(long)c * KSEL + r] = (f16)tile[tx][ty + i * 8];
  }
}

// ---- GY ----
__global__ __launch_bounds__(256) void gy_kernel(const f16* __restrict__ WmT,
    const f16* __restrict__ ZT, const f16* __restrict__ xproj,
    f16* __restrict__ rbuf) {
  GEMM_PROLOG
  int b = blockIdx.z;
  int m0 = blockIdx.y * 128, n0 = blockIdx.x * 128;
  const f16* A = WmT + (long)b * SEQ_ * KSEL;
  const f16* BT = ZT + (long)b * 512 * KSEL;
  const f16* xpb = xproj + (long)b * SEQ_ * 512;
  f16* rb = rbuf + (long)b * SEQ_ * 512;
  for (int k0 = 0; k0 < KSEL; k0 += 32) {
    stage_gll(A, KSEL, m0, k0, As, t);
    stage_gll(BT, KSEL, n0, k0, Bs, t);
    __syncthreads();
    mfma_step(As, Bs, lane, wr, wc, acc);
    __syncthreads();
  }
#pragma unroll
  for (int mi = 0; mi < 4; ++mi)
#pragma unroll
    for (int ni = 0; ni < 4; ++ni) {
      int c = n0 + wc * 64 + ni * 16 + (lane & 15);
      int r0 = m0 + wr * 64 + mi * 16 + (lane >> 4) * 4;
#pragma unroll
      for (int j = 0; j < 4; ++j) {
        long idx = (long)(r0 + j) * 512 + c;
        rb[idx] = (f16)((float)xpb[idx] + acc[mi][ni][j]);
      }
    }
}

// ---- G4 ----
__global__ __launch_bounds__(256) void g4_kernel(const f16* __restrict__ rbuf,
    const float* __restrict__ mean, const float* __restrict__ rstd,
    const float* __restrict__ g4, const float* __restrict__ bl4,
    const f16* __restrict__ W4T, const float* __restrict__ b4,
    float* __restrict__ out) {
  GEMM_PROLOG
  int m0 = blockIdx.y * 128, n0 = blockIdx.x * 128;
  for (int k0 = 0; k0 < 512; k0 += 32) {
    stage_a_ln_f16(rbuf, 512, mean, rstd, g4, bl4, m0, k0, As, t);
    stage_gll(W4T, 512, n0, k0, Bs, t);
    __syncthreads();
    mfma_step(As, Bs, lane, wr, wc, acc);
    __syncthreads();
  }
#pragma unroll
  for (int mi = 0; mi < 4; ++mi)
#pragma unroll
    for (int ni = 0; ni < 4; ++ni) {
      int c = n0 + wc * 64 + ni * 16 + (lane & 15);
      float bias = b4[c];
      int r0 = m0 + wr * 64 + mi * 16 + (lane >> 4) * 4;
#pragma unroll
      for (int j = 0; j < 4; ++j)
        out[(long)(r0 + j) * 512 + c] = acc[mi][ni][j] + bias;
    }
}

// ======================= launcher =======================
extern "C" void kernel_launch(void* const* d_in, const int* in_sizes, int n_in,
                              void* d_out, int out_size, void* d_ws, size_t ws_size,
                              hipStream_t stream) {
  const float* x    = (const float*)d_in[0];
  const float* tau  = (const float*)d_in[1];
  const float* g1   = (const float*)d_in[2];
  const float* bl1  = (const float*)d_in[3];
  const float* W1   = (const float*)d_in[4];
  const float* b1   = (const float*)d_in[5];
  const float* g2   = (const float*)d_in[6];
  const float* bl2  = (const float*)d_in[7];
  const float* W2   = (const float*)d_in[8];
  const float* b2   = (const float*)d_in[9];
  const float* g3   = (const float*)d_in[10];
  const float* bl3  = (const float*)d_in[11];
  const float* W3   = (const float*)d_in[12];
  const float* b3   = (const float*)d_in[13];
  const float* g4   = (const float*)d_in[14];
  const float* bl4  = (const float*)d_in[15];
  const float* W4   = (const float*)d_in[16];
  const float* b4   = (const float*)d_in[17];
  float* out = (float*)d_out;

  const long NTOK = (long)B_ * SEQ_;  // 65536

  // ---- workspace layout ----
  char* ws = (char*)d_ws;
  f16* regA   = (f16*)(ws);                         // 64MB: A2, later xproj
  f16* regB   = (f16*)(ws + (64l << 20));           // 64MB: xsum, later rbuf
  float* Zpart = (float*)(ws + (128l << 20));       // 16MB (split-K=2 fp32)
  f16* W2T    = (f16*)(ws + (144l << 20));          // 8MB
  f16* W1T    = (f16*)(ws + (152l << 20));          // 0.5MB
  f16* W3T    = (f16*)(ws + (153l << 20));          // 0.51MB
  f16* W4T    = (f16*)(ws + (154l << 20));          // 0.5MB
  float* xscore = (float*)(ws + (155l << 20));      // 0.25MB
  float* meanA  = (float*)(ws + (156l << 20));      // 0.25MB
  float* rstdA  = meanA + NTOK;                     // 0.25MB
  float* mean2  = rstdA + NTOK;                     // 64KB
  float* rstd2  = mean2 + B_ * 512;                 // 64KB
  float2* part  = (float2*)(rstd2 + B_ * 512);      // 1MB
  f16* ZT     = (f16*)(ws + (157l << 20));          // 4MB

  // ---- d_out (128MB) doubles as scratch, fully overwritten by G4 ----
  f16* xtok   = (f16*)d_out;                               // [0,64) until g2 reads it
  f16* xprojT = (f16*)d_out;                               // [0,64) written step 5 (xtok dead)
  f16* Wm     = (f16*)((char*)d_out + (64l << 20));        // [64,80)
  f16* WmT    = (f16*)((char*)d_out + (80l << 20));        // [80,96)

  f16* A2    = regA;
  f16* xsum  = regB;
  f16* xproj = regA;   // A2 dead after G2
  f16* rbuf  = regB;   // xsum dead after G3

  dim3 tb(32, 8);

  // weight transposes (f16, [n][k])
  transpose_cvt<float><<<dim3(16, 16, 1), tb, 0, stream>>>(W1, W1T, 512, 512, 0, 0);
  transpose_cvt<float><<<dim3(64, 64, 1), tb, 0, stream>>>(W2, W2T, 2048, 2048, 0, 0);
  transpose_cvt<float><<<dim3(17, 16, 1), tb, 0, stream>>>(W3, W3T, 512, 513, 0, 0);
  transpose_cvt<float><<<dim3(16, 16, 1), tb, 0, stream>>>(W4, W4T, 512, 512, 0, 0);

  // 1) LN1 stats + G1 -> xtok (f16, in d_out)
  rowstats512<<<NTOK / 4, 256, 0, stream>>>(x, meanA, rstdA);
  g1_kernel<<<dim3(4, 512), 256, 0, stream>>>(x, meanA, rstdA, g1, bl1, W1T, b1, xtok);

  // 2) LN2 stats + transposed normalize -> A2, then G2 (256x256 8-phase) -> xsum
  colstats_part<<<B_ * 8, 512, 0, stream>>>(xtok, part);
  colstats_fin<<<64, 256, 0, stream>>>(part, mean2, rstd2);
  trans2_kernel<<<dim3(16, 64, B_), tb, 0, stream>>>(xtok, mean2, rstd2, g2, bl2, A2);
  g2_8p<<<dim3(2, 8, B_), 512, 0, stream>>>(W2T, A2, b2, xtok, xsum);

  // 3) LN3 stats, score column, G3 -> xproj (overwrites A2; xtok now dead)
  rowstats512_f16<<<NTOK / 4, 256, 0, stream>>>(xsum, meanA, rstdA);
  score_kernel<<<NTOK / 4, 256, 0, stream>>>(xsum, meanA, rstdA, g3, bl3, W3T, b3, xscore);
  g3_kernel<<<dim3(4, 512), 256, 0, stream>>>(xsum, meanA, rstdA, g3, bl3, W3T + 512, b3, xproj);

  // 4) top-k -> Wm (f16, d_out[64,80))
  topk_kernel<<<B_, 256, 0, stream>>>(xscore, tau, Wm);

  // 5) transposes for GZ/GY operands (xprojT overwrites dead xtok region)
  transpose_cvt<f16><<<dim3(16, 64, B_), tb, 0, stream>>>(xproj, xprojT, 2048, 512,
      (long)SEQ_ * 512, (long)512 * SEQ_);
  transpose_cvt<f16><<<dim3(64, 4, B_), tb, 0, stream>>>(Wm, WmT, 128, 2048,
      (long)KSEL * SEQ_, (long)SEQ_ * KSEL);

  // 6) Z = Wm @ xproj (split-K=2), then reduce+transpose -> ZT
  gz_kernel<<<dim3(4, 2, B_), 256, 0, stream>>>(Wm, xprojT, Zpart);
  ztrans_kernel<<<dim3(16, 4, B_), tb, 0, stream>>>(Zpart, ZT);

  // 7) rbuf = xproj + Wm^T @ Z (overwrites xsum)
  gy_kernel<<<dim3(4, 16, B_), 256, 0, stream>>>(WmT, ZT, xproj, rbuf);

  // 8) LN4 stats + G4 -> out (overwrites all d_out scratch)
  rowstats512_f16<<<NTOK / 4, 256, 0, stream>>>(rbuf, meanA, rstdA);
  g4_kernel<<<dim3(4, 512), 256, 0, stream>>>(rbuf, meanA, rstdA, g4, bl4, W4T, b4, out);
}